// Round 3
// baseline (186.961 us; speedup 1.0000x reference)
//
#include <hip/hip_runtime.h>

// B=512 batches, MBS=32768 samples, F=512 taps, CD=16 cond dims.
// y[b,n] = sum_{t<512} h[b,t] * x[b,n-t]  (linear conv, zero history)

typedef float f32x16 __attribute__((ext_vector_type(16)));
typedef float f32x4  __attribute__((ext_vector_type(4)));
typedef __bf16 bf16x8 __attribute__((ext_vector_type(8)));

__device__ __forceinline__ unsigned short f2bf(float f) {
    unsigned int u = __float_as_uint(f);
    u += 0x7FFFu + ((u >> 16) & 1u);   // round-to-nearest-even
    return (unsigned short)(u >> 16);
}

__device__ __forceinline__ uint4 pack8(float4 a, float4 b) {
    return make_uint4(
        (unsigned)f2bf(a.x) | ((unsigned)f2bf(a.y) << 16),
        (unsigned)f2bf(a.z) | ((unsigned)f2bf(a.w) << 16),
        (unsigned)f2bf(b.x) | ((unsigned)f2bf(b.y) << 16),
        (unsigned)f2bf(b.z) | ((unsigned)f2bf(b.w) << 16));
}

// ---------------- kA: transpose Wglu/Wf -> bf16 (coalesced via LDS) ----------------
// grid 192: blocks [0,128) WgluT 64x64 tiles, [128,192) WfT tiles.
__global__ __launch_bounds__(256) void kA_t(
    const float* __restrict__ Wglu, const float* __restrict__ Wf,
    unsigned short* __restrict__ WgluT, unsigned short* __restrict__ WfT) {
    __shared__ float ldsF[64 * 65];
    const int blk = blockIdx.x, tid = threadIdx.x;
    const float* src; unsigned short* dst; int tj, tk, srcld;
    if (blk < 128) { tj = blk >> 3; tk = blk & 7; src = Wglu; dst = WgluT; srcld = 1024; }
    else { int b2 = blk - 128; tj = b2 >> 3; tk = b2 & 7; src = Wf; dst = WfT; srcld = 512; }
#pragma unroll
    for (int rr = 0; rr < 16; ++rr) {
        int kl = (tid >> 6) + (rr << 2), jl = tid & 63;
        ldsF[kl * 65 + jl] = src[(size_t)(tk * 64 + kl) * srcld + tj * 64 + jl];
    }
    __syncthreads();
#pragma unroll
    for (int rr = 0; rr < 16; ++rr) {
        int jl = (tid >> 6) + (rr << 2), kl = tid & 63;
        dst[(size_t)(tj * 64 + jl) * 512 + tk * 64 + kl] = f2bf(ldsF[kl * 65 + jl]);
    }
}

// ---------------- kC: fused FiLM -> GLU -> Dense(softsign) -> Bfrag ----------------
// grid 32 blocks x 256 thr; block bi handles batches [16bi, 16bi+16).
// LDS: cfilm 16K | cglu 16K | h 16K | c-stage 1K  (cf/cg XOR-swizzled per 16B unit)
__global__ __launch_bounds__(256) void kC(
    const float* __restrict__ c, const float* __restrict__ W0,
    const float* __restrict__ b0, const float* __restrict__ alpha,
    const float* __restrict__ Wg, const float* __restrict__ bg,
    const float* __restrict__ Wb, const float* __restrict__ bb,
    const unsigned short* __restrict__ WgluT, const unsigned short* __restrict__ WfT,
    const float* __restrict__ bglu, const float* __restrict__ bfv,
    unsigned short* __restrict__ Bfrag) {
    __shared__ __align__(16) unsigned char lds[50176];
    unsigned short* hh = (unsigned short*)(lds + 32768);
    float* cl = (float*)(lds + 49152);
    const int bi = blockIdx.x, tid = threadIdx.x;

    // stage c (16 batches x 16 dims)
    cl[tid] = c[(size_t)(16 * bi) * 16 + tid];
    __syncthreads();

    // stage0: FiLM -> cfilm LDS (swizzled)
#pragma unroll
    for (int ff = 0; ff < 2; ++ff) {
        int f = tid + 256 * ff;
        float w0r[16], wgr[16], wbr[16];
#pragma unroll
        for (int i = 0; i < 16; ++i) {
            w0r[i] = W0[i * 512 + f];
            wgr[i] = Wg[i * 512 + f];
            wbr[i] = Wb[i * 512 + f];
        }
        float b0v = b0[f], av = alpha[f], bgv = bg[f], bbv = bb[f];
#pragma unroll
        for (int bl = 0; bl < 16; ++bl) {
            float d0 = 0.f, dg = 0.f, db = 0.f;
#pragma unroll
            for (int i = 0; i < 16; ++i) {
                float cv = cl[bl * 16 + i];
                d0 += cv * w0r[i]; dg += cv * wgr[i]; db += cv * wbr[i];
            }
            float pre = d0 + b0v;
            float pr = pre >= 0.f ? pre : av * pre;
            float v = pr * (dg + bgv) + (db + bbv);
            int byte = bl * 1024 + f * 2;
            int u = byte >> 4;
            *(unsigned short*)(lds + (((u ^ ((u >> 6) & 7)) << 4) | (byte & 15))) = f2bf(v);
        }
    }
    __syncthreads();

    const int w4 = tid >> 6, l = tid & 63;
    const int lrow = l & 15, lk = 8 * (l >> 4);

    // stage1: GLU  (A = cfilm LDS, B = WgluT from L2), write cglu LDS (swizzled)
    for (int j = 0; j < 8; ++j) {
        int t = w4 * 8 + j;
        int colA = 16 * t + lrow, colG = 512 + colA;
        f32x4 aA = {0.f, 0.f, 0.f, 0.f}, aG = {0.f, 0.f, 0.f, 0.f};
#pragma unroll
        for (int s = 0; s < 16; ++s) {
            int byte = lrow * 1024 + (32 * s + lk) * 2;
            int u = byte >> 4;
            bf16x8 avv = *(const bf16x8*)(lds + ((u ^ ((u >> 6) & 7)) << 4));
            bf16x8 ba = *(const bf16x8*)(WgluT + (size_t)colA * 512 + 32 * s + lk);
            bf16x8 bgt = *(const bf16x8*)(WgluT + (size_t)colG * 512 + 32 * s + lk);
            aA = __builtin_amdgcn_mfma_f32_16x16x32_bf16(avv, ba, aA, 0, 0, 0);
            aG = __builtin_amdgcn_mfma_f32_16x16x32_bf16(avv, bgt, aG, 0, 0, 0);
        }
        float biasA = bglu[colA], biasG = bglu[colG];
#pragma unroll
        for (int r = 0; r < 4; ++r) {
            float ga = aA[r] + biasA, gg = aG[r] + biasG;
            float s = 1.f / (1.f + expf(-gg));
            int m = 4 * (l >> 4) + r;
            int byte = m * 1024 + colA * 2;
            int u = byte >> 4;
            *(unsigned short*)(lds + 16384 + (((u ^ ((u >> 6) & 7)) << 4) | (byte & 15))) = f2bf(ga * s);
        }
    }
    __syncthreads();

    // stage2: Dense + softsign  (A = cglu LDS, B = WfT), write h LDS (plain)
    for (int j = 0; j < 8; ++j) {
        int t = w4 * 8 + j;
        int col = 16 * t + lrow;
        f32x4 acc = {0.f, 0.f, 0.f, 0.f};
#pragma unroll
        for (int s = 0; s < 16; ++s) {
            int byte = lrow * 1024 + (32 * s + lk) * 2;
            int u = byte >> 4;
            bf16x8 avv = *(const bf16x8*)(lds + 16384 + ((u ^ ((u >> 6) & 7)) << 4));
            bf16x8 bv = *(const bf16x8*)(WfT + (size_t)col * 512 + 32 * s + lk);
            acc = __builtin_amdgcn_mfma_f32_16x16x32_bf16(avv, bv, acc, 0, 0, 0);
        }
        float bias = bfv[col];
#pragma unroll
        for (int r = 0; r < 4; ++r) {
            float z = acc[r] + bias;
            float h = z / (1.f + fabsf(z));
            int m = 4 * (l >> 4) + r;
            hh[m * 512 + col] = f2bf(h);
        }
    }
    __syncthreads();

    // stage3: Toeplitz B-fragments -> global. B_c[k][j] = h[16c-16 + j - k].
    for (int bat = 0; bat < 16; ++bat) {
        const unsigned short* hb = hh + bat * 512;
        unsigned short* Bo = Bfrag + (size_t)(16 * bi + bat) * 17408;
        for (int e = tid; e < 2176; e += 256) {
            int cc = e >> 6, ll = e & 63;
            int base = 16 * cc - 16 + (ll & 31) - 8 * (ll >> 5);
            unsigned short vals[8];
#pragma unroll
            for (int i = 0; i < 8; ++i) {
                int idx = base - i;
                vals[i] = (idx >= 0 && idx < 512) ? hb[idx] : (unsigned short)0;
            }
            *(uint4*)(Bo + e * 8) = make_uint4(
                (unsigned)vals[0] | ((unsigned)vals[1] << 16),
                (unsigned)vals[2] | ((unsigned)vals[3] << 16),
                (unsigned)vals[4] | ((unsigned)vals[5] << 16),
                (unsigned)vals[6] | ((unsigned)vals[7] << 16));
        }
    }
}

// ---------------- k4p: pipelined MFMA FIR conv ----------------
// grid 1024 (XCD-swizzled): block = 1 batch-half = 16384 outputs, 4 chunks of 4096.
// Double-buffered LDS x-tile (576 units x 16B per buffer). 4 waves x 1 tile/chunk.
__global__ __launch_bounds__(256, 4) void k4p(
    const float* __restrict__ x, const unsigned short* __restrict__ Bfrag,
    float* __restrict__ y) {
    __shared__ __align__(16) unsigned char smem[18432];
    const int tid = threadIdx.x;
    // XCD swizzle: keep a batch's two blocks on one XCD (shared Bfrag/x-halo in L2)
    const int vb = ((blockIdx.x & 7) << 7) + (blockIdx.x >> 3);
    const int b = vb >> 1;
    const int n0 = (vb & 1) << 14;
    const float* xb = x + (size_t)b * 32768;
    const int w = tid >> 6, l = tid & 63;

    // per-thread staging units (u < 576); swizzled LDS byte offsets are chunk-invariant
    const int u0 = tid, u1 = tid + 256, u2 = tid + 512;
    const int so0 = (u0 ^ ((u0 >> 3) & 7)) << 4;
    const int so1 = (u1 ^ ((u1 >> 3) & 7)) << 4;
    const int so2 = (u2 ^ ((u2 >> 3) & 7)) << 4;

    float4 f0, f1, f2, f3, f4, f5;
    {   // prologue: load chunk 0 (guard: only n0==0 has pre-history, units < 64)
        const float* px = xb + (n0 - 512);
        if (n0 == 0 && tid < 64) {
            f0 = make_float4(0.f, 0.f, 0.f, 0.f); f1 = f0;
        } else {
            f0 = *(const float4*)(px + u0 * 8); f1 = *(const float4*)(px + u0 * 8 + 4);
        }
        f2 = *(const float4*)(px + u1 * 8); f3 = *(const float4*)(px + u1 * 8 + 4);
        if (tid < 64) { f4 = *(const float4*)(px + u2 * 8); f5 = *(const float4*)(px + u2 * 8 + 4); }
    }

    const int lq = 4 * (l & 31) + (l >> 5);
    const int ub = (w << 7) + 66 + lq;
    const unsigned short* Bp = Bfrag + (size_t)b * 17408 + l * 8;

#pragma unroll
    for (int cch = 0; cch < 4; ++cch) {
        unsigned char* wb = smem + ((cch & 1) ? 9216 : 0);
        // convert + LDS write (compiler inserts vmcnt waits for the loads feeding pack8)
        *(uint4*)(wb + so0) = pack8(f0, f1);
        *(uint4*)(wb + so1) = pack8(f2, f3);
        if (tid < 64) *(uint4*)(wb + so2) = pack8(f4, f5);
        // raw barrier: wait LDS writes only; leave global loads/stores in flight
        asm volatile("s_waitcnt lgkmcnt(0)" ::: "memory");
        __builtin_amdgcn_s_barrier();
        asm volatile("" ::: "memory");
        // issue next chunk's loads (overlap with compute below)
        if (cch < 3) {
            const float* px = xb + (n0 + ((cch + 1) << 12) - 512);
            f0 = *(const float4*)(px + u0 * 8); f1 = *(const float4*)(px + u0 * 8 + 4);
            f2 = *(const float4*)(px + u1 * 8); f3 = *(const float4*)(px + u1 * 8 + 4);
            if (tid < 64) { f4 = *(const float4*)(px + u2 * 8); f5 = *(const float4*)(px + u2 * 8 + 4); }
        }
        // compute this chunk: wave w -> tile of 1024 outputs at n0 + 4096*cch + 1024w
        f32x16 acc;
#pragma unroll
        for (int i = 0; i < 16; ++i) acc[i] = 0.f;
        bf16x8 bnext = *(const bf16x8*)(Bp);
        for (int cc = 0; cc < 34; ++cc) {
            bf16x8 bfr = bnext;
            if (cc < 33) bnext = *(const bf16x8*)(Bp + (cc + 1) * 512);
            int uu = ub - 2 * cc;
            bf16x8 a0 = *(const bf16x8*)(wb + ((uu ^ ((uu >> 3) & 7)) << 4));
            acc = __builtin_amdgcn_mfma_f32_32x32x16_bf16(a0, bfr, acc, 0, 0, 0);
        }
        float* yb = y + (size_t)b * 32768 + n0 + (cch << 12) + (w << 10) + (l & 31);
#pragma unroll
        for (int r = 0; r < 16; ++r) {
            int m = (r & 3) + 8 * (r >> 2) + 4 * (l >> 5);   // D: col=l&31, row m
            yb[m << 5] = acc[r];
        }
    }
}

extern "C" void kernel_launch(void* const* d_in, const int* in_sizes, int n_in,
                              void* d_out, int out_size, void* d_ws, size_t ws_size,
                              hipStream_t stream) {
    const float* x    = (const float*)d_in[0];
    const float* c    = (const float*)d_in[1];
    const float* W0   = (const float*)d_in[2];
    const float* b0   = (const float*)d_in[3];
    const float* al   = (const float*)d_in[4];
    const float* Wg   = (const float*)d_in[5];
    const float* bg   = (const float*)d_in[6];
    const float* Wb   = (const float*)d_in[7];
    const float* bb   = (const float*)d_in[8];
    const float* Wglu = (const float*)d_in[9];
    const float* bglu = (const float*)d_in[10];
    const float* Wf   = (const float*)d_in[11];
    const float* bf   = (const float*)d_in[12];
    float* y = (float*)d_out;

    char* ws = (char*)d_ws;
    unsigned short* WgluT = (unsigned short*)(ws);             // 1 MB
    unsigned short* WfT   = (unsigned short*)(ws + 1048576);   // 512 KB
    unsigned short* Bfrag = (unsigned short*)(ws + 1572864);   // 17.8 MB

    kA_t<<<dim3(192), dim3(256), 0, stream>>>(Wglu, Wf, WgluT, WfT);
    kC<<<dim3(32), dim3(256), 0, stream>>>(c, W0, b0, al, Wg, bg, Wb, bb,
                                           WgluT, WfT, bglu, bf, Bfrag);
    k4p<<<dim3(1024), dim3(256), 0, stream>>>(x, Bfrag, y);
}

// Round 4
// 94.992 us; speedup vs baseline: 1.9682x; 1.9682x over previous
//
#include <hip/hip_runtime.h>

// B=512 batches, MBS=32768 samples, F=512 taps, CD=16 cond dims.
// y[b,n] = sum_{t<512} h[b,t] * x[b,n-t]  (linear conv, zero history)

typedef float f32x16 __attribute__((ext_vector_type(16)));
typedef float f32x4  __attribute__((ext_vector_type(4)));
typedef __bf16 bf16x8 __attribute__((ext_vector_type(8)));

__device__ __forceinline__ unsigned short f2bf(float f) {
    unsigned int u = __float_as_uint(f);
    u += 0x7FFFu + ((u >> 16) & 1u);   // round-to-nearest-even
    return (unsigned short)(u >> 16);
}

// ---------------- kA: transpose Wglu/Wf -> bf16 (coalesced via LDS) ----------------
__global__ __launch_bounds__(256) void kA_t(
    const float* __restrict__ Wglu, const float* __restrict__ Wf,
    unsigned short* __restrict__ WgluT, unsigned short* __restrict__ WfT) {
    __shared__ float ldsF[64 * 65];
    const int blk = blockIdx.x, tid = threadIdx.x;
    const float* src; unsigned short* dst; int tj, tk, srcld;
    if (blk < 128) { tj = blk >> 3; tk = blk & 7; src = Wglu; dst = WgluT; srcld = 1024; }
    else { int b2 = blk - 128; tj = b2 >> 3; tk = b2 & 7; src = Wf; dst = WfT; srcld = 512; }
#pragma unroll
    for (int rr = 0; rr < 16; ++rr) {
        int kl = (tid >> 6) + (rr << 2), jl = tid & 63;
        ldsF[kl * 65 + jl] = src[(size_t)(tk * 64 + kl) * srcld + tj * 64 + jl];
    }
    __syncthreads();
#pragma unroll
    for (int rr = 0; rr < 16; ++rr) {
        int jl = (tid >> 6) + (rr << 2), kl = tid & 63;
        dst[(size_t)(tj * 64 + jl) * 512 + tk * 64 + kl] = f2bf(ldsF[kl * 65 + jl]);
    }
}

// ---------------- kC2: fused FiLM -> GLU -> Dense(softsign) -> h (global bf16) ----------------
// grid 32 blocks x 256 thr; block bi handles batches [16bi, 16bi+16).
// LDS: cfilm 16K | cglu 16K | c-stage 1K  (cf/cg XOR-swizzled per 16B unit)
__global__ __launch_bounds__(256) void kC2(
    const float* __restrict__ c, const float* __restrict__ W0,
    const float* __restrict__ b0, const float* __restrict__ alpha,
    const float* __restrict__ Wg, const float* __restrict__ bg,
    const float* __restrict__ Wb, const float* __restrict__ bb,
    const unsigned short* __restrict__ WgluT, const unsigned short* __restrict__ WfT,
    const float* __restrict__ bglu, const float* __restrict__ bfv,
    unsigned short* __restrict__ hbf) {
    __shared__ __align__(16) unsigned char lds[33792];
    float* cl = (float*)(lds + 32768);
    const int bi = blockIdx.x, tid = threadIdx.x;

    cl[tid] = c[(size_t)(16 * bi) * 16 + tid];
    __syncthreads();

    // stage0: FiLM -> cfilm LDS (swizzled)
#pragma unroll
    for (int ff = 0; ff < 2; ++ff) {
        int f = tid + 256 * ff;
        float w0r[16], wgr[16], wbr[16];
#pragma unroll
        for (int i = 0; i < 16; ++i) {
            w0r[i] = W0[i * 512 + f];
            wgr[i] = Wg[i * 512 + f];
            wbr[i] = Wb[i * 512 + f];
        }
        float b0v = b0[f], av = alpha[f], bgv = bg[f], bbv = bb[f];
#pragma unroll
        for (int bl = 0; bl < 16; ++bl) {
            float d0 = 0.f, dg = 0.f, db = 0.f;
#pragma unroll
            for (int i = 0; i < 16; ++i) {
                float cv = cl[bl * 16 + i];
                d0 += cv * w0r[i]; dg += cv * wgr[i]; db += cv * wbr[i];
            }
            float pre = d0 + b0v;
            float pr = pre >= 0.f ? pre : av * pre;
            float v = pr * (dg + bgv) + (db + bbv);
            int byte = bl * 1024 + f * 2;
            int u = byte >> 4;
            *(unsigned short*)(lds + (((u ^ ((u >> 6) & 7)) << 4) | (byte & 15))) = f2bf(v);
        }
    }
    __syncthreads();

    const int w4 = tid >> 6, l = tid & 63;
    const int lrow = l & 15, lk = 8 * (l >> 4);

    // stage1: GLU  (A = cfilm LDS, B = WgluT from L2), write cglu LDS (swizzled)
    for (int j = 0; j < 8; ++j) {
        int t = w4 * 8 + j;
        int colA = 16 * t + lrow, colG = 512 + colA;
        f32x4 aA = {0.f, 0.f, 0.f, 0.f}, aG = {0.f, 0.f, 0.f, 0.f};
#pragma unroll
        for (int s = 0; s < 16; ++s) {
            int byte = lrow * 1024 + (32 * s + lk) * 2;
            int u = byte >> 4;
            bf16x8 avv = *(const bf16x8*)(lds + ((u ^ ((u >> 6) & 7)) << 4));
            bf16x8 ba = *(const bf16x8*)(WgluT + (size_t)colA * 512 + 32 * s + lk);
            bf16x8 bgt = *(const bf16x8*)(WgluT + (size_t)colG * 512 + 32 * s + lk);
            aA = __builtin_amdgcn_mfma_f32_16x16x32_bf16(avv, ba, aA, 0, 0, 0);
            aG = __builtin_amdgcn_mfma_f32_16x16x32_bf16(avv, bgt, aG, 0, 0, 0);
        }
        float biasA = bglu[colA], biasG = bglu[colG];
#pragma unroll
        for (int r = 0; r < 4; ++r) {
            float ga = aA[r] + biasA, gg = aG[r] + biasG;
            float s = 1.f / (1.f + expf(-gg));
            int m = 4 * (l >> 4) + r;
            int byte = m * 1024 + colA * 2;
            int u = byte >> 4;
            *(unsigned short*)(lds + 16384 + (((u ^ ((u >> 6) & 7)) << 4) | (byte & 15))) = f2bf(ga * s);
        }
    }
    __syncthreads();

    // stage2: Dense + softsign  (A = cglu LDS, B = WfT) -> global h (bf16)
    for (int j = 0; j < 8; ++j) {
        int t = w4 * 8 + j;
        int col = 16 * t + lrow;
        f32x4 acc = {0.f, 0.f, 0.f, 0.f};
#pragma unroll
        for (int s = 0; s < 16; ++s) {
            int byte = lrow * 1024 + (32 * s + lk) * 2;
            int u = byte >> 4;
            bf16x8 avv = *(const bf16x8*)(lds + 16384 + ((u ^ ((u >> 6) & 7)) << 4));
            bf16x8 bv = *(const bf16x8*)(WfT + (size_t)col * 512 + 32 * s + lk);
            acc = __builtin_amdgcn_mfma_f32_16x16x32_bf16(avv, bv, acc, 0, 0, 0);
        }
        float bias = bfv[col];
#pragma unroll
        for (int r = 0; r < 4; ++r) {
            float z = acc[r] + bias;
            float h = z / (1.f + fabsf(z));
            int m = 4 * (l >> 4) + r;
            hbf[(size_t)(16 * bi + m) * 512 + col] = f2bf(h);
        }
    }
}

// ---------------- k4n: MFMA FIR conv, B-table in LDS, 16K outputs/block ----------------
// grid 1024: block = (batch, half). 8 waves x 2 tiles(1024 outs each).
// LDS: x tile 2112 units x 16B (XOR-swizzled) [0,33792)
//      h row (512 bf16)                       [33792,34816)
//      Toeplitz B 34 chunks x 64 x 16B        [34816,69632)
__global__ __launch_bounds__(512, 4) void k4n(
    const float* __restrict__ x, const unsigned short* __restrict__ hbf,
    float* __restrict__ y) {
    __shared__ __align__(16) unsigned char smem[69632];
    const int tid = threadIdx.x;
    const int b = blockIdx.x >> 1;
    const int n0 = (blockIdx.x & 1) << 14;

    unsigned short* hs = (unsigned short*)(smem + 33792);
    if (tid < 256)
        ((unsigned int*)hs)[tid] = ((const unsigned int*)(hbf + (size_t)b * 512))[tid];

    // stage x window [n0-512, n0+16384) as bf16, swizzled at 16B-unit level
    const float* xb = x + (size_t)b * 32768;
#pragma unroll
    for (int it = 0; it < 5; ++it) {
        int u = tid + (it << 9);
        if (u < 2112) {
            int g0 = n0 - 512 + (u << 3);
            unsigned short us[8];
            if (g0 >= 0) {
                const float4* p = (const float4*)(xb + g0);
                float4 v0 = p[0], v1 = p[1];
                us[0] = f2bf(v0.x); us[1] = f2bf(v0.y); us[2] = f2bf(v0.z); us[3] = f2bf(v0.w);
                us[4] = f2bf(v1.x); us[5] = f2bf(v1.y); us[6] = f2bf(v1.z); us[7] = f2bf(v1.w);
            } else {
#pragma unroll
                for (int i = 0; i < 8; ++i) us[i] = 0;
            }
            int su = u ^ ((u >> 3) & 7);
            unsigned int q0 = us[0] | ((unsigned int)us[1] << 16);
            unsigned int q1 = us[2] | ((unsigned int)us[3] << 16);
            unsigned int q2 = us[4] | ((unsigned int)us[5] << 16);
            unsigned int q3 = us[6] | ((unsigned int)us[7] << 16);
            *(uint4*)(smem + (su << 4)) = make_uint4(q0, q1, q2, q3);
        }
    }
    __syncthreads();

    // build Toeplitz B fragments: B_c[k][j] = h[16c-16 + j - k], lane-ordered
    unsigned short* Bb = (unsigned short*)(smem + 34816);
    for (int e = tid; e < 34 * 64; e += 512) {
        int cc = e >> 6, ll = e & 63;
        int base = 16 * cc - 16 + (ll & 31) - 8 * (ll >> 5);
        unsigned short vals[8];
#pragma unroll
        for (int i = 0; i < 8; ++i) {
            int idx = base - i;
            vals[i] = (idx >= 0 && idx < 512) ? hs[idx] : (unsigned short)0;
        }
        unsigned int q0 = vals[0] | ((unsigned int)vals[1] << 16);
        unsigned int q1 = vals[2] | ((unsigned int)vals[3] << 16);
        unsigned int q2 = vals[4] | ((unsigned int)vals[5] << 16);
        unsigned int q3 = vals[6] | ((unsigned int)vals[7] << 16);
        *(uint4*)(Bb + e * 8) = make_uint4(q0, q1, q2, q3);
    }
    __syncthreads();

    const int w = tid >> 6, l = tid & 63;                // w in [0,8)
    const int lq = 4 * (l & 31) + (l >> 5);
    const int ubase = (w << 8) + 66 + lq;                // unit idx for c=0, tile 0
    f32x16 acc0, acc1;
#pragma unroll
    for (int i = 0; i < 16; ++i) { acc0[i] = 0.f; acc1[i] = 0.f; }
    const unsigned char* Bp = smem + 34816 + l * 16;
    for (int cc = 0; cc < 34; ++cc) {
        bf16x8 bfr = *(const bf16x8*)(Bp + cc * 1024);
        int u0 = ubase - 2 * cc;
        int u1 = u0 + 128;
        const bf16x8 a0 = *(const bf16x8*)(smem + ((u0 ^ ((u0 >> 3) & 7)) << 4));
        const bf16x8 a1 = *(const bf16x8*)(smem + ((u1 ^ ((u1 >> 3) & 7)) << 4));
        acc0 = __builtin_amdgcn_mfma_f32_32x32x16_bf16(a0, bfr, acc0, 0, 0, 0);
        acc1 = __builtin_amdgcn_mfma_f32_32x32x16_bf16(a1, bfr, acc1, 0, 0, 0);
    }
    // D layout: col = l&31, row m = (r&3) + 8*(r>>2) + 4*(l>>5)
    float* yb = y + (size_t)b * 32768 + n0 + (w << 11) + (l & 31);
#pragma unroll
    for (int r = 0; r < 16; ++r) {
        int m = (r & 3) + 8 * (r >> 2) + 4 * (l >> 5);
        yb[m << 5] = acc0[r];
        yb[1024 + (m << 5)] = acc1[r];
    }
}

extern "C" void kernel_launch(void* const* d_in, const int* in_sizes, int n_in,
                              void* d_out, int out_size, void* d_ws, size_t ws_size,
                              hipStream_t stream) {
    const float* x    = (const float*)d_in[0];
    const float* c    = (const float*)d_in[1];
    const float* W0   = (const float*)d_in[2];
    const float* b0   = (const float*)d_in[3];
    const float* al   = (const float*)d_in[4];
    const float* Wg   = (const float*)d_in[5];
    const float* bg   = (const float*)d_in[6];
    const float* Wb   = (const float*)d_in[7];
    const float* bb   = (const float*)d_in[8];
    const float* Wglu = (const float*)d_in[9];
    const float* bglu = (const float*)d_in[10];
    const float* Wf   = (const float*)d_in[11];
    const float* bf   = (const float*)d_in[12];
    float* y = (float*)d_out;

    char* ws = (char*)d_ws;
    unsigned short* WgluT = (unsigned short*)(ws);             // 1 MB
    unsigned short* WfT   = (unsigned short*)(ws + 1048576);   // 512 KB
    unsigned short* hbf   = (unsigned short*)(ws + 1572864);   // 512 KB

    kA_t<<<dim3(192), dim3(256), 0, stream>>>(Wglu, Wf, WgluT, WfT);
    kC2<<<dim3(32), dim3(256), 0, stream>>>(c, W0, b0, al, Wg, bg, Wb, bb,
                                            WgluT, WfT, bglu, bf, hbf);
    k4n<<<dim3(1024), dim3(512), 0, stream>>>(x, hbf, y);
}

// Round 5
// 53.002 us; speedup vs baseline: 3.5274x; 1.7923x over previous
//
#include <hip/hip_runtime.h>

// B=512 batches, MBS=32768 samples, F=512 taps, CD=16 cond dims.
// y[b,n] = sum_{t<512} h[b,t] * x[b,n-t]  (linear conv, zero history)

typedef float f32x16 __attribute__((ext_vector_type(16)));
typedef float f32x4  __attribute__((ext_vector_type(4)));
typedef __bf16 bf16x8 __attribute__((ext_vector_type(8)));

__device__ __forceinline__ unsigned short f2bf(float f) {
    unsigned int u = __float_as_uint(f);
    u += 0x7FFFu + ((u >> 16) & 1u);   // round-to-nearest-even
    return (unsigned short)(u >> 16);
}

// ---------------- kA: transpose Wglu/Wf -> bf16 + FiLM (wide grid) ----------------
// blocks [0,128): WgluT 64x64 tiles; [128,192): WfT tiles; [192,1216): FiLM.
__global__ __launch_bounds__(256) void kA(
    const float* __restrict__ Wglu, const float* __restrict__ Wf,
    const float* __restrict__ c, const float* __restrict__ W0,
    const float* __restrict__ b0, const float* __restrict__ alpha,
    const float* __restrict__ Wg, const float* __restrict__ bg,
    const float* __restrict__ Wb, const float* __restrict__ bb,
    unsigned short* __restrict__ WgluT, unsigned short* __restrict__ WfT,
    unsigned short* __restrict__ cfilm) {
    const int blk = blockIdx.x, tid = threadIdx.x;
    if (blk < 192) {
        __shared__ float ldsF[64 * 65];
        const float* src; unsigned short* dst; int tj, tk, srcld;
        if (blk < 128) { tj = blk >> 3; tk = blk & 7; src = Wglu; dst = WgluT; srcld = 1024; }
        else { int b2 = blk - 128; tj = b2 >> 3; tk = b2 & 7; src = Wf; dst = WfT; srcld = 512; }
#pragma unroll
        for (int rr = 0; rr < 16; ++rr) {
            int kl = (tid >> 6) + (rr << 2), jl = tid & 63;
            ldsF[kl * 65 + jl] = src[(size_t)(tk * 64 + kl) * srcld + tj * 64 + jl];
        }
        __syncthreads();
#pragma unroll
        for (int rr = 0; rr < 16; ++rr) {
            int jl = (tid >> 6) + (rr << 2), kl = tid & 63;
            dst[(size_t)(tj * 64 + jl) * 512 + tk * 64 + kl] = f2bf(ldsF[kl * 65 + jl]);
        }
    } else {
        int id = (blk - 192) * 256 + tid;           // [0, 262144): b*512+f
        int b = id >> 9, f = id & 511;
        const float* cb = c + b * 16;
        float d0 = 0.f, dg = 0.f, db = 0.f;
#pragma unroll
        for (int i = 0; i < 16; ++i) {
            float cv = cb[i];
            d0 += cv * W0[i * 512 + f];
            dg += cv * Wg[i * 512 + f];
            db += cv * Wb[i * 512 + f];
        }
        float pre = d0 + b0[f];
        float pr = pre >= 0.f ? pre : alpha[f] * pre;
        float v = pr * (dg + bg[f]) + (db + bb[f]);
        cfilm[id] = f2bf(v);
    }
}

// ---------------- k2: GLU GEMM (16x16x32 MFMA), fused a*sigmoid(gate) ----------------
// 1024 waves: 32 m-tiles x 32 col-pair-tiles of 16.
__global__ __launch_bounds__(256) void k2_glu(
    const unsigned short* __restrict__ cfilm, const unsigned short* __restrict__ WgluT,
    const float* __restrict__ bglu, unsigned short* __restrict__ cglu) {
    int wid = (blockIdx.x * 256 + threadIdx.x) >> 6;    // [0,1024)
    int l = threadIdx.x & 63;
    int tm = wid >> 5, tn = wid & 31;
    int row = tm * 16 + (l & 15);
    int col = tn * 16 + (l & 15);
    int kh = 8 * (l >> 4);
    f32x4 accA, accG;
#pragma unroll
    for (int i = 0; i < 4; ++i) { accA[i] = 0.f; accG[i] = 0.f; }
    const unsigned short* ap  = cfilm + row * 512 + kh;
    const unsigned short* bap = WgluT + col * 512 + kh;
    const unsigned short* bgp = WgluT + (512 + col) * 512 + kh;
#pragma unroll
    for (int kc = 0; kc < 16; ++kc) {
        bf16x8 a   = *(const bf16x8*)(ap  + kc * 32);
        bf16x8 ba  = *(const bf16x8*)(bap + kc * 32);
        bf16x8 bgt = *(const bf16x8*)(bgp + kc * 32);
        accA = __builtin_amdgcn_mfma_f32_16x16x32_bf16(a, ba,  accA, 0, 0, 0);
        accG = __builtin_amdgcn_mfma_f32_16x16x32_bf16(a, bgt, accG, 0, 0, 0);
    }
    float biasA = bglu[col], biasG = bglu[512 + col];
#pragma unroll
    for (int r = 0; r < 4; ++r) {
        float ga = accA[r] + biasA;
        float gg = accG[r] + biasG;
        float s = 1.f / (1.f + expf(-gg));
        int m = (l >> 4) * 4 + r;                   // D: col=l&15, row=(l>>4)*4+r
        cglu[(tm * 16 + m) * 512 + col] = f2bf(ga * s);
    }
}

// ---------------- k3: Dense GEMM (16x16x32) + softsign -> filters bf16 ----------------
__global__ __launch_bounds__(256) void k3_filt(
    const unsigned short* __restrict__ cglu, const unsigned short* __restrict__ WfT,
    const float* __restrict__ bfv, unsigned short* __restrict__ hout) {
    int wid = (blockIdx.x * 256 + threadIdx.x) >> 6;    // [0,1024)
    int l = threadIdx.x & 63;
    int tm = wid >> 5, tn = wid & 31;
    int row = tm * 16 + (l & 15);
    int col = tn * 16 + (l & 15);
    int kh = 8 * (l >> 4);
    f32x4 acc;
#pragma unroll
    for (int i = 0; i < 4; ++i) acc[i] = 0.f;
    const unsigned short* ap = cglu + row * 512 + kh;
    const unsigned short* bp = WfT + col * 512 + kh;
#pragma unroll
    for (int kc = 0; kc < 16; ++kc) {
        bf16x8 a  = *(const bf16x8*)(ap + kc * 32);
        bf16x8 bv = *(const bf16x8*)(bp + kc * 32);
        acc = __builtin_amdgcn_mfma_f32_16x16x32_bf16(a, bv, acc, 0, 0, 0);
    }
    float bias = bfv[col];
#pragma unroll
    for (int r = 0; r < 4; ++r) {
        float z = acc[r] + bias;
        float h = z / (1.f + fabsf(z));
        int m = (l >> 4) * 4 + r;
        hout[(tm * 16 + m) * 512 + col] = f2bf(h);
    }
}

// ---------------- k4n: MFMA FIR conv, B-table in LDS, 16K outputs/block ----------------
// grid 1024: block = (batch, half). 8 waves x 2 tiles(1024 outs each).
// LDS: x tile 2112 units x 16B (XOR-swizzled) [0,33792)
//      h row (512 bf16)                       [33792,34816)
//      Toeplitz B 34 chunks x 64 x 16B        [34816,69632)
__global__ __launch_bounds__(512, 4) void k4n(
    const float* __restrict__ x, const unsigned short* __restrict__ hbf,
    float* __restrict__ y) {
    __shared__ __align__(16) unsigned char smem[69632];
    const int tid = threadIdx.x;
    const int b = blockIdx.x >> 1;
    const int n0 = (blockIdx.x & 1) << 14;

    unsigned short* hs = (unsigned short*)(smem + 33792);
    if (tid < 256)
        ((unsigned int*)hs)[tid] = ((const unsigned int*)(hbf + (size_t)b * 512))[tid];

    // stage x window [n0-512, n0+16384) as bf16, swizzled at 16B-unit level
    const float* xb = x + (size_t)b * 32768;
#pragma unroll
    for (int it = 0; it < 5; ++it) {
        int u = tid + (it << 9);
        if (u < 2112) {
            int g0 = n0 - 512 + (u << 3);
            unsigned short us[8];
            if (g0 >= 0) {
                const float4* p = (const float4*)(xb + g0);
                float4 v0 = p[0], v1 = p[1];
                us[0] = f2bf(v0.x); us[1] = f2bf(v0.y); us[2] = f2bf(v0.z); us[3] = f2bf(v0.w);
                us[4] = f2bf(v1.x); us[5] = f2bf(v1.y); us[6] = f2bf(v1.z); us[7] = f2bf(v1.w);
            } else {
#pragma unroll
                for (int i = 0; i < 8; ++i) us[i] = 0;
            }
            int su = u ^ ((u >> 3) & 7);
            unsigned int q0 = us[0] | ((unsigned int)us[1] << 16);
            unsigned int q1 = us[2] | ((unsigned int)us[3] << 16);
            unsigned int q2 = us[4] | ((unsigned int)us[5] << 16);
            unsigned int q3 = us[6] | ((unsigned int)us[7] << 16);
            *(uint4*)(smem + (su << 4)) = make_uint4(q0, q1, q2, q3);
        }
    }
    __syncthreads();

    // build Toeplitz B fragments: B_c[k][j] = h[16c-16 + j - k], lane-ordered
    unsigned short* Bb = (unsigned short*)(smem + 34816);
    for (int e = tid; e < 34 * 64; e += 512) {
        int cc = e >> 6, ll = e & 63;
        int base = 16 * cc - 16 + (ll & 31) - 8 * (ll >> 5);
        unsigned short vals[8];
#pragma unroll
        for (int i = 0; i < 8; ++i) {
            int idx = base - i;
            vals[i] = (idx >= 0 && idx < 512) ? hs[idx] : (unsigned short)0;
        }
        unsigned int q0 = vals[0] | ((unsigned int)vals[1] << 16);
        unsigned int q1 = vals[2] | ((unsigned int)vals[3] << 16);
        unsigned int q2 = vals[4] | ((unsigned int)vals[5] << 16);
        unsigned int q3 = vals[6] | ((unsigned int)vals[7] << 16);
        *(uint4*)(Bb + e * 8) = make_uint4(q0, q1, q2, q3);
    }
    __syncthreads();

    const int w = tid >> 6, l = tid & 63;                // w in [0,8)
    const int lq = 4 * (l & 31) + (l >> 5);
    const int ubase = (w << 8) + 66 + lq;                // unit idx for c=0, tile 0
    f32x16 acc0, acc1;
#pragma unroll
    for (int i = 0; i < 16; ++i) { acc0[i] = 0.f; acc1[i] = 0.f; }
    const unsigned char* Bp = smem + 34816 + l * 16;
    for (int cc = 0; cc < 34; ++cc) {
        bf16x8 bfr = *(const bf16x8*)(Bp + cc * 1024);
        int u0 = ubase - 2 * cc;
        int u1 = u0 + 128;
        const bf16x8 a0 = *(const bf16x8*)(smem + ((u0 ^ ((u0 >> 3) & 7)) << 4));
        const bf16x8 a1 = *(const bf16x8*)(smem + ((u1 ^ ((u1 >> 3) & 7)) << 4));
        acc0 = __builtin_amdgcn_mfma_f32_32x32x16_bf16(a0, bfr, acc0, 0, 0, 0);
        acc1 = __builtin_amdgcn_mfma_f32_32x32x16_bf16(a1, bfr, acc1, 0, 0, 0);
    }
    // D layout: col = l&31, row m = (r&3) + 8*(r>>2) + 4*(l>>5)
    float* yb = y + (size_t)b * 32768 + n0 + (w << 11) + (l & 31);
#pragma unroll
    for (int r = 0; r < 16; ++r) {
        int m = (r & 3) + 8 * (r >> 2) + 4 * (l >> 5);
        yb[m << 5] = acc0[r];
        yb[1024 + (m << 5)] = acc1[r];
    }
}

extern "C" void kernel_launch(void* const* d_in, const int* in_sizes, int n_in,
                              void* d_out, int out_size, void* d_ws, size_t ws_size,
                              hipStream_t stream) {
    const float* x    = (const float*)d_in[0];
    const float* c    = (const float*)d_in[1];
    const float* W0   = (const float*)d_in[2];
    const float* b0   = (const float*)d_in[3];
    const float* al   = (const float*)d_in[4];
    const float* Wg   = (const float*)d_in[5];
    const float* bg   = (const float*)d_in[6];
    const float* Wb   = (const float*)d_in[7];
    const float* bb   = (const float*)d_in[8];
    const float* Wglu = (const float*)d_in[9];
    const float* bglu = (const float*)d_in[10];
    const float* Wf   = (const float*)d_in[11];
    const float* bf   = (const float*)d_in[12];
    float* y = (float*)d_out;

    char* ws = (char*)d_ws;
    unsigned short* cfilm = (unsigned short*)(ws);             // 512 KB
    unsigned short* WgluT = (unsigned short*)(ws + 524288);    // 1 MB
    unsigned short* WfT   = (unsigned short*)(ws + 1572864);   // 512 KB
    unsigned short* cglu  = (unsigned short*)(ws + 2097152);   // 512 KB
    unsigned short* hbf   = (unsigned short*)(ws + 2621440);   // 512 KB

    kA<<<dim3(1216), dim3(256), 0, stream>>>(Wglu, Wf, c, W0, b0, al, Wg, bg, Wb, bb,
                                             WgluT, WfT, cfilm);
    k2_glu<<<dim3(256), dim3(256), 0, stream>>>(cfilm, WgluT, bglu, cglu);
    k3_filt<<<dim3(256), dim3(256), 0, stream>>>(cglu, WfT, bf, hbf);
    k4n<<<dim3(1024), dim3(512), 0, stream>>>(x, hbf, y);
}

// Round 6
// 49.549 us; speedup vs baseline: 3.7733x; 1.0697x over previous
//
#include <hip/hip_runtime.h>

// B=512 batches, MBS=32768 samples, F=512 taps, CD=16 cond dims.
// y[b,n] = sum_{t<512} h[b,t] * x[b,n-t]  (linear conv, zero history)

typedef float f32x16 __attribute__((ext_vector_type(16)));
typedef float f32x4  __attribute__((ext_vector_type(4)));
typedef __bf16 bf16x8 __attribute__((ext_vector_type(8)));

__device__ __forceinline__ unsigned short f2bf(float f) {
    unsigned int u = __float_as_uint(f);
    u += 0x7FFFu + ((u >> 16) & 1u);   // round-to-nearest-even
    return (unsigned short)(u >> 16);
}

__device__ __forceinline__ uint4 pack8n(float4 a, float4 b) {
    bf16x8 v;
    v[0] = (__bf16)a.x; v[1] = (__bf16)a.y; v[2] = (__bf16)a.z; v[3] = (__bf16)a.w;
    v[4] = (__bf16)b.x; v[5] = (__bf16)b.y; v[6] = (__bf16)b.z; v[7] = (__bf16)b.w;
    uint4 r;
    __builtin_memcpy(&r, &v, 16);
    return r;
}

// ---------------- kA: transpose Wglu/Wf -> bf16 + FiLM (wide grid) ----------------
__global__ __launch_bounds__(256) void kA(
    const float* __restrict__ Wglu, const float* __restrict__ Wf,
    const float* __restrict__ c, const float* __restrict__ W0,
    const float* __restrict__ b0, const float* __restrict__ alpha,
    const float* __restrict__ Wg, const float* __restrict__ bg,
    const float* __restrict__ Wb, const float* __restrict__ bb,
    unsigned short* __restrict__ WgluT, unsigned short* __restrict__ WfT,
    unsigned short* __restrict__ cfilm) {
    const int blk = blockIdx.x, tid = threadIdx.x;
    if (blk < 192) {
        __shared__ float ldsF[64 * 65];
        const float* src; unsigned short* dst; int tj, tk, srcld;
        if (blk < 128) { tj = blk >> 3; tk = blk & 7; src = Wglu; dst = WgluT; srcld = 1024; }
        else { int b2 = blk - 128; tj = b2 >> 3; tk = b2 & 7; src = Wf; dst = WfT; srcld = 512; }
#pragma unroll
        for (int rr = 0; rr < 16; ++rr) {
            int kl = (tid >> 6) + (rr << 2), jl = tid & 63;
            ldsF[kl * 65 + jl] = src[(size_t)(tk * 64 + kl) * srcld + tj * 64 + jl];
        }
        __syncthreads();
#pragma unroll
        for (int rr = 0; rr < 16; ++rr) {
            int jl = (tid >> 6) + (rr << 2), kl = tid & 63;
            dst[(size_t)(tj * 64 + jl) * 512 + tk * 64 + kl] = f2bf(ldsF[kl * 65 + jl]);
        }
    } else {
        int id = (blk - 192) * 256 + tid;
        int b = id >> 9, f = id & 511;
        const float* cb = c + b * 16;
        float d0 = 0.f, dg = 0.f, db = 0.f;
#pragma unroll
        for (int i = 0; i < 16; ++i) {
            float cv = cb[i];
            d0 += cv * W0[i * 512 + f];
            dg += cv * Wg[i * 512 + f];
            db += cv * Wb[i * 512 + f];
        }
        float pre = d0 + b0[f];
        float pr = pre >= 0.f ? pre : alpha[f] * pre;
        float v = pr * (dg + bg[f]) + (db + bb[f]);
        cfilm[id] = f2bf(v);
    }
}

// ---------------- k2: GLU GEMM (16x16x32), fused a*sigmoid(gate) ----------------
__global__ __launch_bounds__(256) void k2_glu(
    const unsigned short* __restrict__ cfilm, const unsigned short* __restrict__ WgluT,
    const float* __restrict__ bglu, unsigned short* __restrict__ cglu) {
    int wid = (blockIdx.x * 256 + threadIdx.x) >> 6;
    int l = threadIdx.x & 63;
    int tm = wid >> 5, tn = wid & 31;
    int row = tm * 16 + (l & 15);
    int col = tn * 16 + (l & 15);
    int kh = 8 * (l >> 4);
    f32x4 accA, accG;
#pragma unroll
    for (int i = 0; i < 4; ++i) { accA[i] = 0.f; accG[i] = 0.f; }
    const unsigned short* ap  = cfilm + row * 512 + kh;
    const unsigned short* bap = WgluT + col * 512 + kh;
    const unsigned short* bgp = WgluT + (512 + col) * 512 + kh;
#pragma unroll
    for (int kc = 0; kc < 16; ++kc) {
        bf16x8 a   = *(const bf16x8*)(ap  + kc * 32);
        bf16x8 ba  = *(const bf16x8*)(bap + kc * 32);
        bf16x8 bgt = *(const bf16x8*)(bgp + kc * 32);
        accA = __builtin_amdgcn_mfma_f32_16x16x32_bf16(a, ba,  accA, 0, 0, 0);
        accG = __builtin_amdgcn_mfma_f32_16x16x32_bf16(a, bgt, accG, 0, 0, 0);
    }
    float biasA = bglu[col], biasG = bglu[512 + col];
#pragma unroll
    for (int r = 0; r < 4; ++r) {
        float ga = accA[r] + biasA;
        float gg = accG[r] + biasG;
        float s = 1.f / (1.f + expf(-gg));
        int m = (l >> 4) * 4 + r;
        cglu[(tm * 16 + m) * 512 + col] = f2bf(ga * s);
    }
}

// ---------------- k3: Dense GEMM (16x16x32) + softsign -> filters bf16 ----------------
__global__ __launch_bounds__(256) void k3_filt(
    const unsigned short* __restrict__ cglu, const unsigned short* __restrict__ WfT,
    const float* __restrict__ bfv, unsigned short* __restrict__ hout) {
    int wid = (blockIdx.x * 256 + threadIdx.x) >> 6;
    int l = threadIdx.x & 63;
    int tm = wid >> 5, tn = wid & 31;
    int row = tm * 16 + (l & 15);
    int col = tn * 16 + (l & 15);
    int kh = 8 * (l >> 4);
    f32x4 acc;
#pragma unroll
    for (int i = 0; i < 4; ++i) acc[i] = 0.f;
    const unsigned short* ap = cglu + row * 512 + kh;
    const unsigned short* bp = WfT + col * 512 + kh;
#pragma unroll
    for (int kc = 0; kc < 16; ++kc) {
        bf16x8 a  = *(const bf16x8*)(ap + kc * 32);
        bf16x8 bv = *(const bf16x8*)(bp + kc * 32);
        acc = __builtin_amdgcn_mfma_f32_16x16x32_bf16(a, bv, acc, 0, 0, 0);
    }
    float bias = bfv[col];
#pragma unroll
    for (int r = 0; r < 4; ++r) {
        float z = acc[r] + bias;
        float h = z / (1.f + fabsf(z));
        int m = (l >> 4) * 4 + r;
        hout[(tm * 16 + m) * 512 + col] = f2bf(h);
    }
}

// ---------------- k5: pipelined MFMA FIR conv ----------------
// Block = 1 batch (grid 512, 2 blocks/CU). 4 waves x 2 tiles; 4 chunks of 8192 outs.
// LDS: x dbuf 2 x 1088 units x 16B (XOR-swizzled) [0,34816)
//      hr copies: 8 shifted copies of reversed/padded h, stride 1168B [34816,44160)
//      hs (h row, 512 bf16)                                           [44160,45184)
// B-fragment identity: vals[i] = h[16cc-16+q-8h-i] = hrp[o0-16cc+i], hrp[t]=h[543-t]
// (zero outside t in [32,544)), o0 = 559-q+8h, copy s=o0&7 holds hrp[u+s] -> aligned b128.
__global__ __launch_bounds__(256, 2) void k5(
    const float* __restrict__ x, const unsigned short* __restrict__ hbf,
    float* __restrict__ y) {
    __shared__ __align__(16) unsigned char smem[45184];
    const int tid = threadIdx.x;
    const int b = blockIdx.x;
    const float* xb = x + (size_t)b * 32768;
    unsigned short* hs = (unsigned short*)(smem + 44160);

    ((unsigned int*)hs)[tid] = ((const unsigned int*)(hbf + (size_t)b * 512))[tid];
    __syncthreads();

    // build 8 shifted copies of reversed h: cop[s][j] = hrp[j+s], word-granular
    for (int e = tid; e < 8 * 292; e += 256) {
        int s = e / 292, w = e - s * 292;
        int j0 = 2 * w + s;
        unsigned int v0 = (j0 >= 32 && j0 < 544) ? hs[543 - j0] : 0u;
        unsigned int v1 = (j0 >= 31 && j0 < 543) ? hs[542 - j0] : 0u;
        ((unsigned int*)(smem + 34816))[e] = v0 | (v1 << 16);
    }

    // prologue: stage chunk 0 window [ -512, 8192 ) into buf0
#pragma unroll
    for (int r = 0; r < 5; ++r) {
        int slot = tid + (r << 8);
        if (slot < 1088) {
            int g = slot - 64;                         // unit index rel batch start
            uint4 w4;
            if (g >= 0) {
                float4 a  = *(const float4*)(xb + g * 8);
                float4 b2 = *(const float4*)(xb + g * 8 + 4);
                w4 = pack8n(a, b2);
            } else {
                w4 = make_uint4(0u, 0u, 0u, 0u);
            }
            *(uint4*)(smem + ((slot ^ ((slot >> 3) & 7)) << 4)) = w4;
        }
    }
    __syncthreads();

    const int w = tid >> 6, l = tid & 63;
    const int q = l & 31, hl = l >> 5;
    const int lq = 4 * q + hl;
    const int abase = 66 + (w << 8) + lq;              // A slot for cc=0, tile 0
    const int o0 = 559 - q + 8 * hl;
    const int s8 = o0 & 7;
    const unsigned char* hrb = smem + 34816 + s8 * 1168 + ((o0 - s8) << 1);

    for (int c = 0; c < 4; ++c) {
        const unsigned char* wb = smem + ((c & 1) ? 17408 : 0);
        unsigned char* sb = smem + ((c & 1) ? 0 : 17408);
        float4 La0, La1, La2, La3, La4, Lb0, Lb1, Lb2, Lb3, Lb4;
        if (c < 3) {                                   // issue next-chunk loads
            const float* px = xb + (((c + 1) << 13) - 512);
            La0 = *(const float4*)(px + (tid << 3));           Lb0 = *(const float4*)(px + (tid << 3) + 4);
            La1 = *(const float4*)(px + ((tid + 256) << 3));   Lb1 = *(const float4*)(px + ((tid + 256) << 3) + 4);
            La2 = *(const float4*)(px + ((tid + 512) << 3));   Lb2 = *(const float4*)(px + ((tid + 512) << 3) + 4);
            La3 = *(const float4*)(px + ((tid + 768) << 3));   Lb3 = *(const float4*)(px + ((tid + 768) << 3) + 4);
            if (tid < 64) {
                La4 = *(const float4*)(px + ((tid + 1024) << 3));
                Lb4 = *(const float4*)(px + ((tid + 1024) << 3) + 4);
            }
        }
        f32x16 acc0, acc1;
#pragma unroll
        for (int i = 0; i < 16; ++i) { acc0[i] = 0.f; acc1[i] = 0.f; }
#pragma unroll
        for (int cc = 0; cc < 17; ++cc) {
            bf16x8 bfr = *(const bf16x8*)(hrb - (cc << 5));
            int a0 = abase - 2 * cc, a1 = a0 + 128;
            bf16x8 xa0 = *(const bf16x8*)(wb + ((a0 ^ ((a0 >> 3) & 7)) << 4));
            bf16x8 xa1 = *(const bf16x8*)(wb + ((a1 ^ ((a1 >> 3) & 7)) << 4));
            acc0 = __builtin_amdgcn_mfma_f32_32x32x16_bf16(xa0, bfr, acc0, 0, 0, 0);
            acc1 = __builtin_amdgcn_mfma_f32_32x32x16_bf16(xa1, bfr, acc1, 0, 0, 0);
        }
        if (c < 3) {                                   // convert + write staged tile
            int s0 = tid;
            *(uint4*)(sb + ((s0 ^ ((s0 >> 3) & 7)) << 4)) = pack8n(La0, Lb0);
            int s1 = tid + 256;
            *(uint4*)(sb + ((s1 ^ ((s1 >> 3) & 7)) << 4)) = pack8n(La1, Lb1);
            int s2 = tid + 512;
            *(uint4*)(sb + ((s2 ^ ((s2 >> 3) & 7)) << 4)) = pack8n(La2, Lb2);
            int s3 = tid + 768;
            *(uint4*)(sb + ((s3 ^ ((s3 >> 3) & 7)) << 4)) = pack8n(La3, Lb3);
            if (tid < 64) {
                int s4 = tid + 1024;
                *(uint4*)(sb + ((s4 ^ ((s4 >> 3) & 7)) << 4)) = pack8n(La4, Lb4);
            }
        }
#pragma unroll
        for (int cc = 17; cc < 34; ++cc) {
            bf16x8 bfr = *(const bf16x8*)(hrb - (cc << 5));
            int a0 = abase - 2 * cc, a1 = a0 + 128;
            bf16x8 xa0 = *(const bf16x8*)(wb + ((a0 ^ ((a0 >> 3) & 7)) << 4));
            bf16x8 xa1 = *(const bf16x8*)(wb + ((a1 ^ ((a1 >> 3) & 7)) << 4));
            acc0 = __builtin_amdgcn_mfma_f32_32x32x16_bf16(xa0, bfr, acc0, 0, 0, 0);
            acc1 = __builtin_amdgcn_mfma_f32_32x32x16_bf16(xa1, bfr, acc1, 0, 0, 0);
        }
        // LDS writes visible to all waves before next chunk's reads; stores stay async
        asm volatile("s_waitcnt lgkmcnt(0)" ::: "memory");
        __builtin_amdgcn_s_barrier();
        __builtin_amdgcn_sched_barrier(0);
        // store chunk c (overlaps next iteration's loads/compute)
        float* yb = y + (size_t)b * 32768 + (c << 13) + (w << 11) + q;
#pragma unroll
        for (int r = 0; r < 16; ++r) {
            int m = (r & 3) + 8 * (r >> 2) + 4 * hl;   // D: col=l&31, row m
            yb[m << 5] = acc0[r];
            yb[1024 + (m << 5)] = acc1[r];
        }
    }
}

extern "C" void kernel_launch(void* const* d_in, const int* in_sizes, int n_in,
                              void* d_out, int out_size, void* d_ws, size_t ws_size,
                              hipStream_t stream) {
    const float* x    = (const float*)d_in[0];
    const float* c    = (const float*)d_in[1];
    const float* W0   = (const float*)d_in[2];
    const float* b0   = (const float*)d_in[3];
    const float* al   = (const float*)d_in[4];
    const float* Wg   = (const float*)d_in[5];
    const float* bg   = (const float*)d_in[6];
    const float* Wb   = (const float*)d_in[7];
    const float* bb   = (const float*)d_in[8];
    const float* Wglu = (const float*)d_in[9];
    const float* bglu = (const float*)d_in[10];
    const float* Wf   = (const float*)d_in[11];
    const float* bf   = (const float*)d_in[12];
    float* y = (float*)d_out;

    char* ws = (char*)d_ws;
    unsigned short* cfilm = (unsigned short*)(ws);             // 512 KB
    unsigned short* WgluT = (unsigned short*)(ws + 524288);    // 1 MB
    unsigned short* WfT   = (unsigned short*)(ws + 1572864);   // 512 KB
    unsigned short* cglu  = (unsigned short*)(ws + 2097152);   // 512 KB
    unsigned short* hbf   = (unsigned short*)(ws + 2621440);   // 512 KB

    kA<<<dim3(1216), dim3(256), 0, stream>>>(Wglu, Wf, c, W0, b0, al, Wg, bg, Wb, bb,
                                             WgluT, WfT, cfilm);
    k2_glu<<<dim3(256), dim3(256), 0, stream>>>(cfilm, WgluT, bglu, cglu);
    k3_filt<<<dim3(256), dim3(256), 0, stream>>>(cglu, WfT, bf, hbf);
    k5<<<dim3(512), dim3(256), 0, stream>>>(x, hbf, y);
}